// Round 10
// baseline (379.482 us; speedup 1.0000x reference)
//
#include <hip/hip_runtime.h>
#include <hip/hip_bf16.h>
#include <stdint.h>

#define BB 16
#define TMAX 30
#define FEAT 512
#define RNN 512
#define ATTN 512
#define VOCABP1 111
#define HWD 512
#define PH 10
#define PW 66
#define PROWS 660

typedef unsigned short u16;
typedef __attribute__((ext_vector_type(8))) unsigned short us8v;
typedef __attribute__((ext_vector_type(8))) short short8;
typedef __attribute__((ext_vector_type(4))) float f32x4;

__device__ __forceinline__ float b2f(u16 b){
  unsigned int u = ((unsigned int)b) << 16;
  return __builtin_bit_cast(float, u);
}
__device__ __forceinline__ u16 f2b(float x){   // RNE
  unsigned int u = __builtin_bit_cast(unsigned int, x);
  unsigned int r = u + 0x7FFFu + ((u >> 16) & 1u);
  return (u16)(r >> 16);
}
__device__ __forceinline__ float fsig(float x){ return __fdividef(1.0f, 1.0f + __expf(-x)); }
__device__ __forceinline__ float ftanhf(float x){ return 1.0f - __fdividef(2.0f, __expf(2.0f*x) + 1.0f); }

// ================= prep: 5 regions =================
__global__ __launch_bounds__(256) void k_prep(
    const float* __restrict__ feats, const float* __restrict__ fconv_w,
    const float* __restrict__ att_Wih, const float* __restrict__ att_Whh,
    const float* __restrict__ scw, const float* __restrict__ embw,
    const float* __restrict__ att_bih, const float* __restrict__ att_bhh,
    const float* __restrict__ encoded, const float* __restrict__ dec_Wih,
    const float* __restrict__ dec_bih, const float* __restrict__ dec_bhh,
    u16* __restrict__ featsP, u16* __restrict__ wB,
    u16* __restrict__ wA1, u16* __restrict__ wA2,
    u16* __restrict__ wScw, u16* __restrict__ wEmb, float* __restrict__ bsumI,
    u16* __restrict__ h0b, float* __restrict__ c0){
  __shared__ float tile[64*65];
  int blk = blockIdx.x, tid = threadIdx.x;
  if (blk < 1024){
    // R0: features [B,C,HW] -> padded bf16 [B,PROWS,C]
    int hwb = blk & 7, cb = (blk >> 3) & 7, b = blk >> 6;
    int c0_ = cb*64, hw0 = hwb*64;
    int tx = tid & 63, ty = tid >> 6;
#pragma unroll
    for (int r = 0; r < 16; ++r){
      int cl = ty*16 + r;
      tile[cl*65 + tx] = feats[((size_t)(b*FEAT + c0_ + cl))*HWD + hw0 + tx];
    }
    __syncthreads();
#pragma unroll
    for (int r = 0; r < 16; ++r){
      int hwl = ty*16 + r;
      int hw = hw0 + hwl;
      int rowP = hw + 2*(hw >> 6) + 67;
      featsP[((size_t)b*PROWS + rowP)*FEAT + c0_ + tx] = f2b(tile[tx*65 + hwl]);
    }
  } else if (blk < 2048){
    // R1: conv weights -> bf16 wB[k9][o][c]
    int idx = (blk - 1024)*256 + tid;
#pragma unroll
    for (int j = 0; j < 9; ++j){
      int e = j*262144 + idx;
      int c = e & 511, n = (e >> 9) & 511, k9 = e >> 18;
      wB[e] = f2b(fconv_w[((size_t)(n*512 + c))*9 + k9]);
    }
  } else if (blk < 2560){
    // R2: gate-interleaved K-concat packs + misc bf16 converts
    int gtid = (blk - 2048)*256 + tid;          // 0..131071
    for (int e = gtid; e < 2097152; e += 131072){
      int mp = e >> 10, k = e & 1023;
      int u = mp >> 2, g = mp & 3;
      int row = u + 512*g;
      if (k < 512){
        wA1[e] = f2b(att_Wih[(size_t)row*512 + k]);
        wA2[e] = f2b(att_Whh[(size_t)row*512 + k]);
      } else {
        wA1[e] = f2b(att_Whh[(size_t)row*512 + k - 512]);
        wA2[e] = f2b(att_Wih[(size_t)row*512 + k - 512]);
      }
    }
    for (int e = gtid; e < 262144; e += 131072) wScw[e] = f2b(scw[e]);
    if (gtid < VOCABP1*512) wEmb[gtid] = f2b(embw[gtid]);
    if (gtid < 2048){
      int u = gtid >> 2, g = gtid & 3, row = u + 512*g;
      bsumI[gtid] = att_bih[row] + att_bhh[row];
    }
  } else if (blk < 2688){
    // R3: zero featsP border rows
    int blkl = blk - 2560;
    for (int r = blkl; r < 148*BB; r += 128){
      int b = r / 148, j = r % 148;
      int rowP;
      if (j < 66) rowP = j;
      else if (j < 132) rowP = 594 + (j - 66);
      else if (j < 140) rowP = (j - 132 + 1)*66;
      else rowP = (j - 140 + 1)*66 + 65;
      ((unsigned int*)&featsP[((size_t)b*PROWS + rowP)*FEAT])[tid] = 0u;
    }
  } else {
    // R4: decoder LSTM (zero state) -> h0 bf16, c0 fp32; blocks 2688..2703
    int b = blk - 2688;
    for (int i = tid; i < 512; i += 256) tile[i] = encoded[b*512 + i];
    __syncthreads();
#pragma unroll
    for (int p = 0; p < 2; ++p){
      int u = p*256 + tid;
      float ai = 0.f, ag = 0.f, ao = 0.f;
      const float* wi = dec_Wih + (size_t)u*512;
      const float* wg = dec_Wih + (size_t)(u + 1024)*512;
      const float* wo = dec_Wih + (size_t)(u + 1536)*512;
      for (int k = 0; k < 512; k += 4){
        float x0 = tile[k], x1 = tile[k+1], x2 = tile[k+2], x3 = tile[k+3];
        float4 a4 = *(const float4*)&wi[k]; ai += a4.x*x0 + a4.y*x1 + a4.z*x2 + a4.w*x3;
        float4 b4 = *(const float4*)&wg[k]; ag += b4.x*x0 + b4.y*x1 + b4.z*x2 + b4.w*x3;
        float4 c4 = *(const float4*)&wo[k]; ao += c4.x*x0 + c4.y*x1 + c4.z*x2 + c4.w*x3;
      }
      float gi = ai + dec_bih[u]      + dec_bhh[u];
      float gg = ag + dec_bih[u+1024] + dec_bhh[u+1024];
      float go = ao + dec_bih[u+1536] + dec_bhh[u+1536];
      float cv = fsig(gi)*ftanhf(gg);
      float hv = fsig(go)*ftanhf(cv);
      c0[b*512 + u] = cv;
      h0b[b*512 + u] = f2b(hv);
    }
  }
}

// ================= D2: conv (blk<512) + gemm1-with-LSTM1-epilogue (blk>=512) =================
__global__ __launch_bounds__(256) void k_conv_gemm1(
    const u16* __restrict__ featsP, const u16* __restrict__ wB,
    const float* __restrict__ bias, float* __restrict__ fpe,
    const u16* __restrict__ wA1, const u16* __restrict__ wEmb,
    const u16* __restrict__ h0b, const int* __restrict__ gt,
    const float* __restrict__ bsumI, const float* __restrict__ c0,
    u16* __restrict__ h1b, float* __restrict__ c1){
  __shared__ __align__(16) u16 As[128*32];
  __shared__ __align__(16) u16 Bs[64*32];
  int blk = blockIdx.x;
  int tid = threadIdx.x, lane = tid & 63, wave = tid >> 6;
  int wm = wave >> 1, wn = wave & 1;
  int kk = (lane & 3)*8;
  int rA0 = 32*wave + (lane >> 2);
  int rA1 = rA0 + 16;
  int nloc = 16*wave + (lane >> 2);
  int arow = wm*64 + (lane & 15);
  int akc  = (lane >> 4)*8;
  int brow = wn*32 + (lane & 15);
  f32x4 acc[4][2];
#pragma unroll
  for (int i=0;i<4;++i)
#pragma unroll
    for (int j=0;j<2;++j) acc[i][j] = (f32x4){0.f,0.f,0.f,0.f};
  int col = lane & 15;
  int rbase = (lane >> 4)*4;

  if (blk < 512){
    int m0 = (blk & 63)*128, n0 = (blk >> 6)*64;
    int mA0 = m0 + rA0, mA1 = m0 + rA1;
    long baseA0 = ((long)((mA0 >> 9)*PH + ((mA0 >> 6) & 7) + 1)*PW + (mA0 & 63) + 1)*FEAT + kk;
    long baseA1 = ((long)((mA1 >> 9)*PH + ((mA1 >> 6) & 7) + 1)*PW + (mA1 & 63) + 1)*FEAT + kk;
    long baseB = (long)(n0 + nloc)*512 + kk;
    us8v a0c, a1c, bc;
    {
      long dA = (long)(-1*PW - 1)*FEAT;
      a0c = *(const us8v*)(featsP + baseA0 + dA);
      a1c = *(const us8v*)(featsP + baseA1 + dA);
      bc  = *(const us8v*)(wB + baseB);
    }
    for (int ks = 0; ks < 144; ++ks){
      __syncthreads();
      *(us8v*)&As[rA0*32 + kk] = a0c;
      *(us8v*)&As[rA1*32 + kk] = a1c;
      *(us8v*)&Bs[nloc*32 + kk] = bc;
      __syncthreads();
      if (ks < 143){
        int kn = ks + 1;
        int o = kn >> 4;
        int c0_ = (kn & 15) << 5;
        int dy = o/3 - 1, dx = o - (o/3)*3 - 1;
        long dA = (long)(dy*PW + dx)*FEAT + c0_;
        long dB = (long)o*(512*512) + c0_;
        a0c = *(const us8v*)(featsP + baseA0 + dA);
        a1c = *(const us8v*)(featsP + baseA1 + dA);
        bc  = *(const us8v*)(wB + baseB + dB);
      }
      short8 a[4], bfr[2];
#pragma unroll
      for (int mt=0; mt<4; ++mt) a[mt] = *(const short8*)&As[(arow + mt*16)*32 + akc];
#pragma unroll
      for (int nt=0; nt<2; ++nt) bfr[nt] = *(const short8*)&Bs[(brow + nt*16)*32 + akc];
#pragma unroll
      for (int mt=0; mt<4; ++mt)
#pragma unroll
        for (int nt=0; nt<2; ++nt)
          acc[mt][nt] = __builtin_amdgcn_mfma_f32_16x16x32_bf16(a[mt], bfr[nt], acc[mt][nt], 0, 0, 0);
    }
#pragma unroll
    for (int mt=0; mt<4; ++mt){
#pragma unroll
      for (int nt=0; nt<2; ++nt){
        int gn = n0 + wn*32 + nt*16 + col;
        float bv = bias[gn];
#pragma unroll
        for (int r=0; r<4; ++r){
          int gm = m0 + wm*64 + mt*16 + rbase + r;
          fpe[(size_t)gm*ATTN + gn] = __expf(2.0f*(acc[mt][nt][r] + bv));
        }
      }
    }
  } else {
    int b2 = blk - 512;
    int m0 = (b2 & 15)*128, n0 = (b2 >> 4)*64;
    const u16* aptr0 = wA1 + (size_t)(m0 + rA0)*1024 + kk;
    const u16* aptr1 = wA1 + (size_t)(m0 + rA1)*1024 + kk;
    int btc = n0 + nloc; if (btc > 479) btc = 479;
    const u16* bp1 = wEmb + (size_t)gt[btc]*512 + kk;
    const u16* bp2 = h0b + (size_t)(btc/TMAX)*512 + kk;
    us8v a0c = *(const us8v*)aptr0;
    us8v a1c = *(const us8v*)aptr1;
    us8v bc  = *(const us8v*)bp1;
    for (int ks = 0; ks < 32; ++ks){
      __syncthreads();
      *(us8v*)&As[rA0*32 + kk] = a0c;
      *(us8v*)&As[rA1*32 + kk] = a1c;
      *(us8v*)&Bs[nloc*32 + kk] = bc;
      __syncthreads();
      if (ks < 31){
        int kn = ks + 1;
        int off = kn*32;
        a0c = *(const us8v*)(aptr0 + off);
        a1c = *(const us8v*)(aptr1 + off);
        bc  = (kn < 16) ? *(const us8v*)(bp1 + off) : *(const us8v*)(bp2 + off - 512);
      }
      short8 a[4], bfr[2];
#pragma unroll
      for (int mt=0; mt<4; ++mt) a[mt] = *(const short8*)&As[(arow + mt*16)*32 + akc];
#pragma unroll
      for (int nt=0; nt<2; ++nt) bfr[nt] = *(const short8*)&Bs[(brow + nt*16)*32 + akc];
#pragma unroll
      for (int mt=0; mt<4; ++mt)
#pragma unroll
        for (int nt=0; nt<2; ++nt)
          acc[mt][nt] = __builtin_amdgcn_mfma_f32_16x16x32_bf16(a[mt], bfr[nt], acc[mt][nt], 0, 0, 0);
    }
#pragma unroll
    for (int mt=0; mt<4; ++mt){
#pragma unroll
      for (int nt=0; nt<2; ++nt){
        int gbt = n0 + wn*32 + nt*16 + col;
        if (gbt < 480){
          int gm0 = m0 + wm*64 + mt*16 + rbase;
          int u = gm0 >> 2;
          float4 bs = *(const float4*)&bsumI[gm0];
          float vi = acc[mt][nt][0] + bs.x;
          float vf = acc[mt][nt][1] + bs.y;
          float vg = acc[mt][nt][2] + bs.z;
          float vo = acc[mt][nt][3] + bs.w;
          float cp = c0[(gbt/TMAX)*512 + u];
          float cv = fsig(vf)*cp + fsig(vi)*ftanhf(vg);
          float hv = fsig(vo)*ftanhf(cv);
          h1b[(size_t)gbt*512 + u] = f2b(hv);
          c1[(size_t)gbt*512 + u] = cv;
        }
      }
    }
  }
}

// ================= D3: gemm2 (gates2 = [Whh|Wih]@[h1;h0]) with LSTM2 epilogue =================
__global__ __launch_bounds__(256) void k_gemm_lstm2(
    const u16* __restrict__ wA2, const u16* __restrict__ h1bsrc, const u16* __restrict__ h0b,
    const float* __restrict__ bsumI, const float* __restrict__ c1, u16* __restrict__ h2b){
  __shared__ __align__(16) u16 As[128*32];
  __shared__ __align__(16) u16 Bs[64*32];
  int m0 = blockIdx.x*128, n0 = blockIdx.y*64;
  int tid = threadIdx.x, lane = tid & 63, wave = tid >> 6;
  int wm = wave >> 1, wn = wave & 1;
  int kk = (lane & 3)*8;
  int rA0 = 32*wave + (lane >> 2);
  int rA1 = rA0 + 16;
  int nloc = 16*wave + (lane >> 2);
  const u16* aptr0 = wA2 + (size_t)(m0 + rA0)*1024 + kk;
  const u16* aptr1 = wA2 + (size_t)(m0 + rA1)*1024 + kk;
  int btc = n0 + nloc; if (btc > 479) btc = 479;
  const u16* bp1 = h1bsrc + (size_t)btc*512 + kk;
  const u16* bp2 = h0b + (size_t)(btc/TMAX)*512 + kk;
  f32x4 acc[4][2];
#pragma unroll
  for (int i=0;i<4;++i)
#pragma unroll
    for (int j=0;j<2;++j) acc[i][j] = (f32x4){0.f,0.f,0.f,0.f};
  int arow = wm*64 + (lane & 15);
  int akc  = (lane >> 4)*8;
  int brow = wn*32 + (lane & 15);

  us8v a0c = *(const us8v*)aptr0;
  us8v a1c = *(const us8v*)aptr1;
  us8v bc  = *(const us8v*)bp1;
  for (int ks = 0; ks < 32; ++ks){
    __syncthreads();
    *(us8v*)&As[rA0*32 + kk] = a0c;
    *(us8v*)&As[rA1*32 + kk] = a1c;
    *(us8v*)&Bs[nloc*32 + kk] = bc;
    __syncthreads();
    if (ks < 31){
      int kn = ks + 1;
      int off = kn*32;
      a0c = *(const us8v*)(aptr0 + off);
      a1c = *(const us8v*)(aptr1 + off);
      bc  = (kn < 16) ? *(const us8v*)(bp1 + off) : *(const us8v*)(bp2 + off - 512);
    }
    short8 a[4], bfr[2];
#pragma unroll
    for (int mt=0; mt<4; ++mt) a[mt] = *(const short8*)&As[(arow + mt*16)*32 + akc];
#pragma unroll
    for (int nt=0; nt<2; ++nt) bfr[nt] = *(const short8*)&Bs[(brow + nt*16)*32 + akc];
#pragma unroll
    for (int mt=0; mt<4; ++mt)
#pragma unroll
      for (int nt=0; nt<2; ++nt)
        acc[mt][nt] = __builtin_amdgcn_mfma_f32_16x16x32_bf16(a[mt], bfr[nt], acc[mt][nt], 0, 0, 0);
  }
  int col = lane & 15;
  int rbase = (lane >> 4)*4;
#pragma unroll
  for (int mt=0; mt<4; ++mt){
#pragma unroll
    for (int nt=0; nt<2; ++nt){
      int gbt = n0 + wn*32 + nt*16 + col;
      if (gbt < 480){
        int gm0 = m0 + wm*64 + mt*16 + rbase;
        int u = gm0 >> 2;
        float4 bs = *(const float4*)&bsumI[gm0];
        float vi = acc[mt][nt][0] + bs.x;
        float vf = acc[mt][nt][1] + bs.y;
        float vg = acc[mt][nt][2] + bs.z;
        float vo = acc[mt][nt][3] + bs.w;
        float cp = c1[(size_t)gbt*512 + u];
        float cv = fsig(vf)*cp + fsig(vi)*ftanhf(vg);
        float hv = fsig(vo)*ftanhf(cv);
        h2b[(size_t)gbt*512 + u] = f2b(hv);
      }
    }
  }
}

// ================= D4: spe = exp(2 * scw @ h2) =================
__global__ __launch_bounds__(256) void k_gemm_spe(const u16* __restrict__ A, const u16* __restrict__ X,
                                                  float* __restrict__ G){
  __shared__ __align__(16) u16 As[128*32];
  __shared__ __align__(16) u16 Bs[64*32];
  int m0 = blockIdx.x*128, n0 = blockIdx.y*64;
  int tid = threadIdx.x, lane = tid & 63, wave = tid >> 6;
  int wm = wave >> 1, wn = wave & 1;
  int kk = (lane & 3)*8;
  int rA0 = 32*wave + (lane >> 2);
  int rA1 = rA0 + 16;
  int nloc = 16*wave + (lane >> 2);
  const u16* aptr0 = A + (size_t)(m0 + rA0)*512 + kk;
  const u16* aptr1 = A + (size_t)(m0 + rA1)*512 + kk;
  int btc = n0 + nloc; if (btc > 479) btc = 479;
  const u16* bptr = X + (size_t)btc*512 + kk;
  f32x4 acc[4][2];
#pragma unroll
  for (int i=0;i<4;++i)
#pragma unroll
    for (int j=0;j<2;++j) acc[i][j] = (f32x4){0.f,0.f,0.f,0.f};
  int arow = wm*64 + (lane & 15);
  int akc  = (lane >> 4)*8;
  int brow = wn*32 + (lane & 15);

  us8v a0c = *(const us8v*)aptr0;
  us8v a1c = *(const us8v*)aptr1;
  us8v bc  = *(const us8v*)bptr;
  for (int ks = 0; ks < 16; ++ks){
    __syncthreads();
    *(us8v*)&As[rA0*32 + kk] = a0c;
    *(us8v*)&As[rA1*32 + kk] = a1c;
    *(us8v*)&Bs[nloc*32 + kk] = bc;
    __syncthreads();
    if (ks < 15){
      int off = (ks + 1)*32;
      a0c = *(const us8v*)(aptr0 + off);
      a1c = *(const us8v*)(aptr1 + off);
      bc  = *(const us8v*)(bptr + off);
    }
    short8 a[4], bfr[2];
#pragma unroll
    for (int mt=0; mt<4; ++mt) a[mt] = *(const short8*)&As[(arow + mt*16)*32 + akc];
#pragma unroll
    for (int nt=0; nt<2; ++nt) bfr[nt] = *(const short8*)&Bs[(brow + nt*16)*32 + akc];
#pragma unroll
    for (int mt=0; mt<4; ++mt)
#pragma unroll
      for (int nt=0; nt<2; ++nt)
        acc[mt][nt] = __builtin_amdgcn_mfma_f32_16x16x32_bf16(a[mt], bfr[nt], acc[mt][nt], 0, 0, 0);
  }
  int col = lane & 15;
  int rbase = (lane >> 4)*4;
#pragma unroll
  for (int mt=0; mt<4; ++mt){
#pragma unroll
    for (int nt=0; nt<2; ++nt){
      int gbt = n0 + wn*32 + nt*16 + col;
      if (gbt < 480){
#pragma unroll
        for (int r=0; r<4; ++r){
          int gm = m0 + wm*64 + mt*16 + rbase + r;
          G[(size_t)gbt*512 + gm] = __expf(2.0f*acc[mt][nt][r]);
        }
      }
    }
  }
}

// ================= D5: scores via e^{2f}*e^{2s} factorization =================
__global__ __launch_bounds__(512) void k_sc(const float* __restrict__ fpe, const float* __restrict__ spe,
                                            const float* __restrict__ apw, float* __restrict__ sc){
  __shared__ float spL[8][516];
  __shared__ float w2L[512];
  int b = blockIdx.x, hw0 = blockIdx.y * 32, t0 = blockIdx.z * 8;
  int tid = threadIdx.x, lane = tid & 63, wave = tid >> 6;
  for (int i = tid; i < 8*512; i += 512){
    int t = i >> 9, a = i & 511;
    int tg = t0 + t;
    spL[t][a] = (tg < TMAX) ? spe[((size_t)(b*TMAX + tg))*ATTN + a] : 0.f;
  }
  w2L[tid] = -2.0f * apw[tid];
  __syncthreads();
#pragma unroll
  for (int r = 0; r < 4; ++r){
    int row = hw0 + wave*4 + r;
    const float* frow = fpe + ((size_t)b*HWD + row)*ATTN;
    float acc[8];
#pragma unroll
    for (int t=0;t<8;++t) acc[t] = 0.f;
#pragma unroll
    for (int a0 = 0; a0 < 8; ++a0){
      int a = a0*64 + lane;
      float ef = frow[a];
      float w2 = w2L[a];
#pragma unroll
      for (int t=0;t<8;++t){
        float d = __builtin_fmaf(ef, spL[t][a], 1.0f);
        acc[t] = __builtin_fmaf(w2, __builtin_amdgcn_rcpf(d), acc[t]);
      }
    }
#pragma unroll
    for (int t=0;t<8;++t){
      float s = acc[t];
#pragma unroll
      for (int off = 32; off; off >>= 1) s += __shfl_xor(s, off);
      if (lane == 0 && (t0 + t) < TMAX) sc[((size_t)(b*TMAX + t0 + t))*HWD + row] = s;
    }
  }
}

// ================= D6: softmax + glimpse + logits, one block per (b,t) =================
__global__ __launch_bounds__(512) void k_tail(const float* __restrict__ sc, const u16* __restrict__ featsP,
                                              const float* __restrict__ outw, const float* __restrict__ outb,
                                              float* __restrict__ out){
  __shared__ float scL[512];
  __shared__ float red[8];
  __shared__ float gl[512];
  __shared__ float part[4][128];
  int bt = blockIdx.x, b = bt / TMAX;
  int tid = threadIdx.x, lane = tid & 63, wave = tid >> 6;
  float v = sc[(size_t)bt*HWD + tid];
  float m = v;
#pragma unroll
  for (int off = 32; off; off >>= 1) m = fmaxf(m, __shfl_xor(m, off));
  if (lane == 0) red[wave] = m;
  __syncthreads();
  float mx = red[0];
#pragma unroll
  for (int i = 1; i < 8; ++i) mx = fmaxf(mx, red[i]);
  float e = __expf(v - mx);
  float s = e;
#pragma unroll
  for (int off = 32; off; off >>= 1) s += __shfl_xor(s, off);
  __syncthreads();
  if (lane == 0) red[wave] = s;
  __syncthreads();
  float tot = 0.f;
#pragma unroll
  for (int i = 0; i < 8; ++i) tot += red[i];
  scL[tid] = e * __builtin_amdgcn_rcpf(tot);
  __syncthreads();
  // glimpse: thread = channel c
  const u16* fb = featsP + (size_t)b*PROWS*FEAT;
  float acc = 0.f;
  for (int hw = 0; hw < HWD; ++hw){
    int rowP = hw + 2*(hw >> 6) + 67;
    acc = __builtin_fmaf(b2f(fb[(size_t)rowP*FEAT + tid]), scL[hw], acc);
  }
  gl[tid] = acc;
  __syncthreads();
  int vg = tid >> 7, vv = tid & 127;
  int vc = vv < VOCABP1 ? vv : VOCABP1-1;
  const float* wr = outw + (size_t)vc*512 + vg*128;
  float so = 0.f;
  for (int k = 0; k < 128; k += 4){
    float4 w4 = *(const float4*)&wr[k];
    so += w4.x*gl[vg*128+k] + w4.y*gl[vg*128+k+1] + w4.z*gl[vg*128+k+2] + w4.w*gl[vg*128+k+3];
  }
  part[vg][vv] = so;
  __syncthreads();
  if (tid < VOCABP1)
    out[(size_t)bt*VOCABP1 + tid] = part[0][tid] + part[1][tid] + part[2][tid] + part[3][tid] + outb[tid];
}

extern "C" void kernel_launch(void* const* d_in, const int* in_sizes, int n_in,
                              void* d_out, int out_size, void* d_ws, size_t ws_size,
                              hipStream_t stream){
  (void)in_sizes; (void)n_in; (void)out_size; (void)ws_size;
  const float* features = (const float*)d_in[0];
  const float* encoded  = (const float*)d_in[1];
  const float* embed_w  = (const float*)d_in[2];
  const float* dec_Wih  = (const float*)d_in[3];
  const float* dec_bih  = (const float*)d_in[5];
  const float* dec_bhh  = (const float*)d_in[6];
  const float* att_Wih  = (const float*)d_in[7];
  const float* att_Whh  = (const float*)d_in[8];
  const float* att_bih  = (const float*)d_in[9];
  const float* att_bhh  = (const float*)d_in[10];
  const float* fconv_w  = (const float*)d_in[11];
  const float* fconv_b  = (const float*)d_in[12];
  const float* scw      = (const float*)d_in[13];
  const float* apw      = (const float*)d_in[14];
  const float* outw     = (const float*)d_in[15];
  const float* outb     = (const float*)d_in[16];
  const int* gt         = (const int*)d_in[17];

  char* ws = (char*)d_ws;
  u16*  featsP = (u16*)(ws + 0);            // 10,813,440
  u16*  wB     = (u16*)(ws + 10813440);     //  4,718,592
  float* fpe   = (float*)(ws + 15532032);   // 16,777,216
  u16*  wA1    = (u16*)(ws + 32309248);     //  4,194,304
  u16*  wA2    = (u16*)(ws + 36503552);     //  4,194,304
  u16*  wScw   = (u16*)(ws + 40697856);     //    524,288
  u16*  wEmb   = (u16*)(ws + 41222144);     //    113,664
  float* bsumI = (float*)(ws + 41335808);   //      8,192
  u16*  h0b    = (u16*)(ws + 41344000);     //     16,384
  float* c0    = (float*)(ws + 41360384);   //     32,768
  u16*  h1b    = (u16*)(ws + 41393152);     //    491,520
  float* c1    = (float*)(ws + 41884672);   //    983,040
  u16*  h2b    = (u16*)(ws + 42867712);     //    491,520
  float* spe   = (float*)(ws + 43359232);   //    983,040
  float* sc    = (float*)(ws + 44342272);   //    983,040 -> total 45,325,312 B

  k_prep<<<dim3(2704), 256, 0, stream>>>(features, fconv_w, att_Wih, att_Whh, scw, embed_w,
                                         att_bih, att_bhh, encoded, dec_Wih, dec_bih, dec_bhh,
                                         featsP, wB, wA1, wA2, wScw, wEmb, bsumI, h0b, c0);
  k_conv_gemm1<<<dim3(640), 256, 0, stream>>>(featsP, wB, fconv_b, fpe,
                                              wA1, wEmb, h0b, gt, bsumI, c0, h1b, c1);
  k_gemm_lstm2<<<dim3(16,8), 256, 0, stream>>>(wA2, h1b, h0b, bsumI, c1, h2b);
  k_gemm_spe<<<dim3(4,8), 256, 0, stream>>>(wScw, h2b, spe);
  k_sc<<<dim3(16,16,4), 512, 0, stream>>>(fpe, spe, apw, sc);
  k_tail<<<dim3(480), 512, 0, stream>>>(sc, featsP, outw, outb, (float*)d_out);
}

// Round 11
// 297.925 us; speedup vs baseline: 1.2738x; 1.2738x over previous
//
#include <hip/hip_runtime.h>
#include <hip/hip_bf16.h>
#include <stdint.h>

#define BB 16
#define TMAX 30
#define FEAT 512
#define RNN 512
#define ATTN 512
#define VOCABP1 111
#define HWD 512
#define PH 10
#define PW 66
#define PROWS 660

typedef unsigned short u16;
typedef __attribute__((ext_vector_type(8))) unsigned short us8v;
typedef __attribute__((ext_vector_type(8))) short short8;
typedef __attribute__((ext_vector_type(4))) float f32x4;

__device__ __forceinline__ float b2f(u16 b){
  unsigned int u = ((unsigned int)b) << 16;
  return __builtin_bit_cast(float, u);
}
__device__ __forceinline__ u16 f2b(float x){   // RNE
  unsigned int u = __builtin_bit_cast(unsigned int, x);
  unsigned int r = u + 0x7FFFu + ((u >> 16) & 1u);
  return (u16)(r >> 16);
}
__device__ __forceinline__ float fsig(float x){ return __fdividef(1.0f, 1.0f + __expf(-x)); }
__device__ __forceinline__ float ftanhf(float x){ return 1.0f - __fdividef(2.0f, __expf(2.0f*x) + 1.0f); }

// ================= prep: 5 regions =================
__global__ __launch_bounds__(256) void k_prep(
    const float* __restrict__ feats, const float* __restrict__ fconv_w,
    const float* __restrict__ att_Wih, const float* __restrict__ att_Whh,
    const float* __restrict__ scw, const float* __restrict__ embw,
    const float* __restrict__ att_bih, const float* __restrict__ att_bhh,
    const float* __restrict__ encoded, const float* __restrict__ dec_Wih,
    const float* __restrict__ dec_bih, const float* __restrict__ dec_bhh,
    u16* __restrict__ featsP, u16* __restrict__ wB,
    u16* __restrict__ wA1, u16* __restrict__ wA2,
    u16* __restrict__ wScw, u16* __restrict__ wEmb, float* __restrict__ bsumI,
    u16* __restrict__ h0b, float* __restrict__ c0){
  __shared__ float tile[64*65];
  int blk = blockIdx.x, tid = threadIdx.x;
  if (blk < 1024){
    // R0: features [B,C,HW] -> padded bf16 [B,PROWS,C]
    int hwb = blk & 7, cb = (blk >> 3) & 7, b = blk >> 6;
    int c0_ = cb*64, hw0 = hwb*64;
    int tx = tid & 63, ty = tid >> 6;
#pragma unroll
    for (int r = 0; r < 16; ++r){
      int cl = ty*16 + r;
      tile[cl*65 + tx] = feats[((size_t)(b*FEAT + c0_ + cl))*HWD + hw0 + tx];
    }
    __syncthreads();
#pragma unroll
    for (int r = 0; r < 16; ++r){
      int hwl = ty*16 + r;
      int hw = hw0 + hwl;
      int rowP = hw + 2*(hw >> 6) + 67;
      featsP[((size_t)b*PROWS + rowP)*FEAT + c0_ + tx] = f2b(tile[tx*65 + hwl]);
    }
  } else if (blk < 2048){
    // R1: conv weights -> bf16 wB[k9][o][c]; thread = (n,c): 9 consecutive reads, coalesced writes
    int idx = (blk - 1024)*256 + tid;        // idx = n*512 + c, 0..262143
    const float* src = fconv_w + (size_t)idx*9;
    float v[9];
#pragma unroll
    for (int j = 0; j < 9; ++j) v[j] = src[j];
#pragma unroll
    for (int j = 0; j < 9; ++j) wB[(size_t)j*262144 + idx] = f2b(v[j]);
  } else if (blk < 2560){
    // R2: gate-interleaved K-concat packs + misc bf16 converts
    int gtid = (blk - 2048)*256 + tid;          // 0..131071
    for (int e = gtid; e < 2097152; e += 131072){
      int mp = e >> 10, k = e & 1023;
      int u = mp >> 2, g = mp & 3;
      int row = u + 512*g;
      if (k < 512){
        wA1[e] = f2b(att_Wih[(size_t)row*512 + k]);
        wA2[e] = f2b(att_Whh[(size_t)row*512 + k]);
      } else {
        wA1[e] = f2b(att_Whh[(size_t)row*512 + k - 512]);
        wA2[e] = f2b(att_Wih[(size_t)row*512 + k - 512]);
      }
    }
    for (int e = gtid; e < 262144; e += 131072) wScw[e] = f2b(scw[e]);
    if (gtid < VOCABP1*512) wEmb[gtid] = f2b(embw[gtid]);
    if (gtid < 2048){
      int u = gtid >> 2, g = gtid & 3, row = u + 512*g;
      bsumI[gtid] = att_bih[row] + att_bhh[row];
    }
  } else if (blk < 2688){
    // R3: zero featsP border rows
    int blkl = blk - 2560;
    for (int r = blkl; r < 148*BB; r += 128){
      int b = r / 148, j = r % 148;
      int rowP;
      if (j < 66) rowP = j;
      else if (j < 132) rowP = 594 + (j - 66);
      else if (j < 140) rowP = (j - 132 + 1)*66;
      else rowP = (j - 140 + 1)*66 + 65;
      ((unsigned int*)&featsP[((size_t)b*PROWS + rowP)*FEAT])[tid] = 0u;
    }
  } else {
    // R4: decoder LSTM via MFMA (gate-interleaved rows, on-the-fly fp32->bf16)
    u16* As = (u16*)tile;              // 128*32 u16 = 8KB
    u16* Bs = ((u16*)tile) + 128*32;   // 64*32 u16 = 4KB
    int m0 = (blk - 2688)*128;
    int lane = tid & 63, wave = tid >> 6;
    int wm = wave >> 1, wn = wave & 1;
    int kk = (lane & 3)*8;
    int rA0 = 32*wave + (lane >> 2);
    int rA1 = rA0 + 16;
    // gate-interleaved source rows: row' = u*4+g -> row = u + 512*g
    int srcR0 = ((m0 + rA0) >> 2) + 512*((m0 + rA0) & 3);
    int srcR1 = ((m0 + rA1) >> 2) + 512*((m0 + rA1) & 3);
    const float* ap0 = dec_Wih + (size_t)srcR0*512 + kk;
    const float* ap1 = dec_Wih + (size_t)srcR1*512 + kk;
    int nloc = 16*wave + (lane >> 2);
    int bcl = nloc < BB ? nloc : BB-1;
    const float* bp = encoded + (size_t)bcl*512 + kk;
    f32x4 acc[4][2];
#pragma unroll
    for (int i=0;i<4;++i)
#pragma unroll
      for (int j=0;j<2;++j) acc[i][j] = (f32x4){0.f,0.f,0.f,0.f};
    int arow = wm*64 + (lane & 15);
    int akc  = (lane >> 4)*8;
    int brow = wn*32 + (lane & 15);
    for (int ks = 0; ks < 16; ++ks){
      int off = ks*32;
      us8v a0c, a1c, bc;
#pragma unroll
      for (int j = 0; j < 8; ++j){
        a0c[j] = f2b(ap0[off + j]);
        a1c[j] = f2b(ap1[off + j]);
        bc[j]  = f2b(bp[off + j]);
      }
      __syncthreads();
      *(us8v*)&As[rA0*32 + kk] = a0c;
      *(us8v*)&As[rA1*32 + kk] = a1c;
      *(us8v*)&Bs[nloc*32 + kk] = bc;
      __syncthreads();
      short8 a[4], bfr[2];
#pragma unroll
      for (int mt=0; mt<4; ++mt) a[mt] = *(const short8*)&As[(arow + mt*16)*32 + akc];
#pragma unroll
      for (int nt=0; nt<2; ++nt) bfr[nt] = *(const short8*)&Bs[(brow + nt*16)*32 + akc];
#pragma unroll
      for (int mt=0; mt<4; ++mt)
#pragma unroll
        for (int nt=0; nt<2; ++nt)
          acc[mt][nt] = __builtin_amdgcn_mfma_f32_16x16x32_bf16(a[mt], bfr[nt], acc[mt][nt], 0, 0, 0);
    }
    int col = lane & 15;
    int rbase = (lane >> 4)*4;
#pragma unroll
    for (int mt=0; mt<4; ++mt){
#pragma unroll
      for (int nt=0; nt<2; ++nt){
        int b = wn*32 + nt*16 + col;
        if (b < BB){
          int gm0 = m0 + wm*64 + mt*16 + rbase;
          int u = gm0 >> 2;
          float vi = acc[mt][nt][0] + dec_bih[u]      + dec_bhh[u];
          float vg = acc[mt][nt][2] + dec_bih[u+1024] + dec_bhh[u+1024];
          float vo = acc[mt][nt][3] + dec_bih[u+1536] + dec_bhh[u+1536];
          float cv = fsig(vi)*ftanhf(vg);
          float hv = fsig(vo)*ftanhf(cv);
          c0[b*512 + u] = cv;
          h0b[b*512 + u] = f2b(hv);
        }
      }
    }
  }
}

// ================= D2: conv (blk<512) + gemm1-with-LSTM1-epilogue (blk>=512) =================
__global__ __launch_bounds__(256) void k_conv_gemm1(
    const u16* __restrict__ featsP, const u16* __restrict__ wB,
    const float* __restrict__ bias, float* __restrict__ fpe,
    const u16* __restrict__ wA1, const u16* __restrict__ wEmb,
    const u16* __restrict__ h0b, const int* __restrict__ gt,
    const float* __restrict__ bsumI, const float* __restrict__ c0,
    u16* __restrict__ h1b, float* __restrict__ c1){
  __shared__ __align__(16) u16 As[128*32];
  __shared__ __align__(16) u16 Bs[64*32];
  int blk = blockIdx.x;
  int tid = threadIdx.x, lane = tid & 63, wave = tid >> 6;
  int wm = wave >> 1, wn = wave & 1;
  int kk = (lane & 3)*8;
  int rA0 = 32*wave + (lane >> 2);
  int rA1 = rA0 + 16;
  int nloc = 16*wave + (lane >> 2);
  int arow = wm*64 + (lane & 15);
  int akc  = (lane >> 4)*8;
  int brow = wn*32 + (lane & 15);
  f32x4 acc[4][2];
#pragma unroll
  for (int i=0;i<4;++i)
#pragma unroll
    for (int j=0;j<2;++j) acc[i][j] = (f32x4){0.f,0.f,0.f,0.f};
  int col = lane & 15;
  int rbase = (lane >> 4)*4;

  if (blk < 512){
    int m0 = (blk & 63)*128, n0 = (blk >> 6)*64;
    int mA0 = m0 + rA0, mA1 = m0 + rA1;
    long baseA0 = ((long)((mA0 >> 9)*PH + ((mA0 >> 6) & 7) + 1)*PW + (mA0 & 63) + 1)*FEAT + kk;
    long baseA1 = ((long)((mA1 >> 9)*PH + ((mA1 >> 6) & 7) + 1)*PW + (mA1 & 63) + 1)*FEAT + kk;
    long baseB = (long)(n0 + nloc)*512 + kk;
    us8v a0c, a1c, bc;
    {
      long dA = (long)(-1*PW - 1)*FEAT;
      a0c = *(const us8v*)(featsP + baseA0 + dA);
      a1c = *(const us8v*)(featsP + baseA1 + dA);
      bc  = *(const us8v*)(wB + baseB);
    }
    for (int ks = 0; ks < 144; ++ks){
      __syncthreads();
      *(us8v*)&As[rA0*32 + kk] = a0c;
      *(us8v*)&As[rA1*32 + kk] = a1c;
      *(us8v*)&Bs[nloc*32 + kk] = bc;
      __syncthreads();
      if (ks < 143){
        int kn = ks + 1;
        int o = kn >> 4;
        int c0_ = (kn & 15) << 5;
        int dy = o/3 - 1, dx = o - (o/3)*3 - 1;
        long dA = (long)(dy*PW + dx)*FEAT + c0_;
        long dB = (long)o*(512*512) + c0_;
        a0c = *(const us8v*)(featsP + baseA0 + dA);
        a1c = *(const us8v*)(featsP + baseA1 + dA);
        bc  = *(const us8v*)(wB + baseB + dB);
      }
      short8 a[4], bfr[2];
#pragma unroll
      for (int mt=0; mt<4; ++mt) a[mt] = *(const short8*)&As[(arow + mt*16)*32 + akc];
#pragma unroll
      for (int nt=0; nt<2; ++nt) bfr[nt] = *(const short8*)&Bs[(brow + nt*16)*32 + akc];
#pragma unroll
      for (int mt=0; mt<4; ++mt)
#pragma unroll
        for (int nt=0; nt<2; ++nt)
          acc[mt][nt] = __builtin_amdgcn_mfma_f32_16x16x32_bf16(a[mt], bfr[nt], acc[mt][nt], 0, 0, 0);
    }
#pragma unroll
    for (int mt=0; mt<4; ++mt){
#pragma unroll
      for (int nt=0; nt<2; ++nt){
        int gn = n0 + wn*32 + nt*16 + col;
        float bv = bias[gn];
#pragma unroll
        for (int r=0; r<4; ++r){
          int gm = m0 + wm*64 + mt*16 + rbase + r;
          fpe[(size_t)gm*ATTN + gn] = __expf(2.0f*(acc[mt][nt][r] + bv));
        }
      }
    }
  } else {
    int b2 = blk - 512;
    int m0 = (b2 & 15)*128, n0 = (b2 >> 4)*64;
    const u16* aptr0 = wA1 + (size_t)(m0 + rA0)*1024 + kk;
    const u16* aptr1 = wA1 + (size_t)(m0 + rA1)*1024 + kk;
    int btc = n0 + nloc; if (btc > 479) btc = 479;
    const u16* bp1 = wEmb + (size_t)gt[btc]*512 + kk;
    const u16* bp2 = h0b + (size_t)(btc/TMAX)*512 + kk;
    us8v a0c = *(const us8v*)aptr0;
    us8v a1c = *(const us8v*)aptr1;
    us8v bc  = *(const us8v*)bp1;
    for (int ks = 0; ks < 32; ++ks){
      __syncthreads();
      *(us8v*)&As[rA0*32 + kk] = a0c;
      *(us8v*)&As[rA1*32 + kk] = a1c;
      *(us8v*)&Bs[nloc*32 + kk] = bc;
      __syncthreads();
      if (ks < 31){
        int kn = ks + 1;
        int off = kn*32;
        a0c = *(const us8v*)(aptr0 + off);
        a1c = *(const us8v*)(aptr1 + off);
        bc  = (kn < 16) ? *(const us8v*)(bp1 + off) : *(const us8v*)(bp2 + off - 512);
      }
      short8 a[4], bfr[2];
#pragma unroll
      for (int mt=0; mt<4; ++mt) a[mt] = *(const short8*)&As[(arow + mt*16)*32 + akc];
#pragma unroll
      for (int nt=0; nt<2; ++nt) bfr[nt] = *(const short8*)&Bs[(brow + nt*16)*32 + akc];
#pragma unroll
      for (int mt=0; mt<4; ++mt)
#pragma unroll
        for (int nt=0; nt<2; ++nt)
          acc[mt][nt] = __builtin_amdgcn_mfma_f32_16x16x32_bf16(a[mt], bfr[nt], acc[mt][nt], 0, 0, 0);
    }
#pragma unroll
    for (int mt=0; mt<4; ++mt){
#pragma unroll
      for (int nt=0; nt<2; ++nt){
        int gbt = n0 + wn*32 + nt*16 + col;
        if (gbt < 480){
          int gm0 = m0 + wm*64 + mt*16 + rbase;
          int u = gm0 >> 2;
          float4 bs = *(const float4*)&bsumI[gm0];
          float vi = acc[mt][nt][0] + bs.x;
          float vf = acc[mt][nt][1] + bs.y;
          float vg = acc[mt][nt][2] + bs.z;
          float vo = acc[mt][nt][3] + bs.w;
          float cp = c0[(gbt/TMAX)*512 + u];
          float cv = fsig(vf)*cp + fsig(vi)*ftanhf(vg);
          float hv = fsig(vo)*ftanhf(cv);
          h1b[(size_t)gbt*512 + u] = f2b(hv);
          c1[(size_t)gbt*512 + u] = cv;
        }
      }
    }
  }
}

// ================= D3: gemm2 (gates2 = [Whh|Wih]@[h1;h0]) with LSTM2 epilogue =================
__global__ __launch_bounds__(256) void k_gemm_lstm2(
    const u16* __restrict__ wA2, const u16* __restrict__ h1bsrc, const u16* __restrict__ h0b,
    const float* __restrict__ bsumI, const float* __restrict__ c1, u16* __restrict__ h2b){
  __shared__ __align__(16) u16 As[128*32];
  __shared__ __align__(16) u16 Bs[64*32];
  int m0 = blockIdx.x*128, n0 = blockIdx.y*64;
  int tid = threadIdx.x, lane = tid & 63, wave = tid >> 6;
  int wm = wave >> 1, wn = wave & 1;
  int kk = (lane & 3)*8;
  int rA0 = 32*wave + (lane >> 2);
  int rA1 = rA0 + 16;
  int nloc = 16*wave + (lane >> 2);
  const u16* aptr0 = wA2 + (size_t)(m0 + rA0)*1024 + kk;
  const u16* aptr1 = wA2 + (size_t)(m0 + rA1)*1024 + kk;
  int btc = n0 + nloc; if (btc > 479) btc = 479;
  const u16* bp1 = h1bsrc + (size_t)btc*512 + kk;
  const u16* bp2 = h0b + (size_t)(btc/TMAX)*512 + kk;
  f32x4 acc[4][2];
#pragma unroll
  for (int i=0;i<4;++i)
#pragma unroll
    for (int j=0;j<2;++j) acc[i][j] = (f32x4){0.f,0.f,0.f,0.f};
  int arow = wm*64 + (lane & 15);
  int akc  = (lane >> 4)*8;
  int brow = wn*32 + (lane & 15);

  us8v a0c = *(const us8v*)aptr0;
  us8v a1c = *(const us8v*)aptr1;
  us8v bc  = *(const us8v*)bp1;
  for (int ks = 0; ks < 32; ++ks){
    __syncthreads();
    *(us8v*)&As[rA0*32 + kk] = a0c;
    *(us8v*)&As[rA1*32 + kk] = a1c;
    *(us8v*)&Bs[nloc*32 + kk] = bc;
    __syncthreads();
    if (ks < 31){
      int kn = ks + 1;
      int off = kn*32;
      a0c = *(const us8v*)(aptr0 + off);
      a1c = *(const us8v*)(aptr1 + off);
      bc  = (kn < 16) ? *(const us8v*)(bp1 + off) : *(const us8v*)(bp2 + off - 512);
    }
    short8 a[4], bfr[2];
#pragma unroll
    for (int mt=0; mt<4; ++mt) a[mt] = *(const short8*)&As[(arow + mt*16)*32 + akc];
#pragma unroll
    for (int nt=0; nt<2; ++nt) bfr[nt] = *(const short8*)&Bs[(brow + nt*16)*32 + akc];
#pragma unroll
    for (int mt=0; mt<4; ++mt)
#pragma unroll
      for (int nt=0; nt<2; ++nt)
        acc[mt][nt] = __builtin_amdgcn_mfma_f32_16x16x32_bf16(a[mt], bfr[nt], acc[mt][nt], 0, 0, 0);
  }
  int col = lane & 15;
  int rbase = (lane >> 4)*4;
#pragma unroll
  for (int mt=0; mt<4; ++mt){
#pragma unroll
    for (int nt=0; nt<2; ++nt){
      int gbt = n0 + wn*32 + nt*16 + col;
      if (gbt < 480){
        int gm0 = m0 + wm*64 + mt*16 + rbase;
        int u = gm0 >> 2;
        float4 bs = *(const float4*)&bsumI[gm0];
        float vi = acc[mt][nt][0] + bs.x;
        float vf = acc[mt][nt][1] + bs.y;
        float vg = acc[mt][nt][2] + bs.z;
        float vo = acc[mt][nt][3] + bs.w;
        float cp = c1[(size_t)gbt*512 + u];
        float cv = fsig(vf)*cp + fsig(vi)*ftanhf(vg);
        float hv = fsig(vo)*ftanhf(cv);
        h2b[(size_t)gbt*512 + u] = f2b(hv);
      }
    }
  }
}

// ================= D4: spe = exp(2 * scw @ h2) =================
__global__ __launch_bounds__(256) void k_gemm_spe(const u16* __restrict__ A, const u16* __restrict__ X,
                                                  float* __restrict__ G){
  __shared__ __align__(16) u16 As[128*32];
  __shared__ __align__(16) u16 Bs[64*32];
  int m0 = blockIdx.x*128, n0 = blockIdx.y*64;
  int tid = threadIdx.x, lane = tid & 63, wave = tid >> 6;
  int wm = wave >> 1, wn = wave & 1;
  int kk = (lane & 3)*8;
  int rA0 = 32*wave + (lane >> 2);
  int rA1 = rA0 + 16;
  int nloc = 16*wave + (lane >> 2);
  const u16* aptr0 = A + (size_t)(m0 + rA0)*512 + kk;
  const u16* aptr1 = A + (size_t)(m0 + rA1)*512 + kk;
  int btc = n0 + nloc; if (btc > 479) btc = 479;
  const u16* bptr = X + (size_t)btc*512 + kk;
  f32x4 acc[4][2];
#pragma unroll
  for (int i=0;i<4;++i)
#pragma unroll
    for (int j=0;j<2;++j) acc[i][j] = (f32x4){0.f,0.f,0.f,0.f};
  int arow = wm*64 + (lane & 15);
  int akc  = (lane >> 4)*8;
  int brow = wn*32 + (lane & 15);

  us8v a0c = *(const us8v*)aptr0;
  us8v a1c = *(const us8v*)aptr1;
  us8v bc  = *(const us8v*)bptr;
  for (int ks = 0; ks < 16; ++ks){
    __syncthreads();
    *(us8v*)&As[rA0*32 + kk] = a0c;
    *(us8v*)&As[rA1*32 + kk] = a1c;
    *(us8v*)&Bs[nloc*32 + kk] = bc;
    __syncthreads();
    if (ks < 15){
      int off = (ks + 1)*32;
      a0c = *(const us8v*)(aptr0 + off);
      a1c = *(const us8v*)(aptr1 + off);
      bc  = *(const us8v*)(bptr + off);
    }
    short8 a[4], bfr[2];
#pragma unroll
    for (int mt=0; mt<4; ++mt) a[mt] = *(const short8*)&As[(arow + mt*16)*32 + akc];
#pragma unroll
    for (int nt=0; nt<2; ++nt) bfr[nt] = *(const short8*)&Bs[(brow + nt*16)*32 + akc];
#pragma unroll
    for (int mt=0; mt<4; ++mt)
#pragma unroll
      for (int nt=0; nt<2; ++nt)
        acc[mt][nt] = __builtin_amdgcn_mfma_f32_16x16x32_bf16(a[mt], bfr[nt], acc[mt][nt], 0, 0, 0);
  }
  int col = lane & 15;
  int rbase = (lane >> 4)*4;
#pragma unroll
  for (int mt=0; mt<4; ++mt){
#pragma unroll
    for (int nt=0; nt<2; ++nt){
      int gbt = n0 + wn*32 + nt*16 + col;
      if (gbt < 480){
#pragma unroll
        for (int r=0; r<4; ++r){
          int gm = m0 + wm*64 + mt*16 + rbase + r;
          G[(size_t)gbt*512 + gm] = __expf(2.0f*acc[mt][nt][r]);
        }
      }
    }
  }
}

// ================= D5: scores via e^{2f}*e^{2s} factorization =================
__global__ __launch_bounds__(512) void k_sc(const float* __restrict__ fpe, const float* __restrict__ spe,
                                            const float* __restrict__ apw, float* __restrict__ sc){
  __shared__ float spL[8][516];
  __shared__ float w2L[512];
  int b = blockIdx.x, hw0 = blockIdx.y * 32, t0 = blockIdx.z * 8;
  int tid = threadIdx.x, lane = tid & 63, wave = tid >> 6;
  for (int i = tid; i < 8*512; i += 512){
    int t = i >> 9, a = i & 511;
    int tg = t0 + t;
    spL[t][a] = (tg < TMAX) ? spe[((size_t)(b*TMAX + tg))*ATTN + a] : 0.f;
  }
  w2L[tid] = -2.0f * apw[tid];
  __syncthreads();
#pragma unroll
  for (int r = 0; r < 4; ++r){
    int row = hw0 + wave*4 + r;
    const float* frow = fpe + ((size_t)b*HWD + row)*ATTN;
    float acc[8];
#pragma unroll
    for (int t=0;t<8;++t) acc[t] = 0.f;
#pragma unroll
    for (int a0 = 0; a0 < 8; ++a0){
      int a = a0*64 + lane;
      float ef = frow[a];
      float w2 = w2L[a];
#pragma unroll
      for (int t=0;t<8;++t){
        float d = __builtin_fmaf(ef, spL[t][a], 1.0f);
        acc[t] = __builtin_fmaf(w2, __builtin_amdgcn_rcpf(d), acc[t]);
      }
    }
#pragma unroll
    for (int t=0;t<8;++t){
      float s = acc[t];
#pragma unroll
      for (int off = 32; off; off >>= 1) s += __shfl_xor(s, off);
      if (lane == 0 && (t0 + t) < TMAX) sc[((size_t)(b*TMAX + t0 + t))*HWD + row] = s;
    }
  }
}

// ================= D6: softmax + glimpse + logits, one block per (b,t) =================
__global__ __launch_bounds__(512) void k_tail(const float* __restrict__ sc, const u16* __restrict__ featsP,
                                              const float* __restrict__ outw, const float* __restrict__ outb,
                                              float* __restrict__ out){
  __shared__ float scL[512];
  __shared__ float red[8];
  __shared__ float gl[512];
  __shared__ float part[4][128];
  int bt = blockIdx.x, b = bt / TMAX;
  int tid = threadIdx.x, lane = tid & 63, wave = tid >> 6;
  float v = sc[(size_t)bt*HWD + tid];
  float m = v;
#pragma unroll
  for (int off = 32; off; off >>= 1) m = fmaxf(m, __shfl_xor(m, off));
  if (lane == 0) red[wave] = m;
  __syncthreads();
  float mx = red[0];
#pragma unroll
  for (int i = 1; i < 8; ++i) mx = fmaxf(mx, red[i]);
  float e = __expf(v - mx);
  float s = e;
#pragma unroll
  for (int off = 32; off; off >>= 1) s += __shfl_xor(s, off);
  __syncthreads();
  if (lane == 0) red[wave] = s;
  __syncthreads();
  float tot = 0.f;
#pragma unroll
  for (int i = 0; i < 8; ++i) tot += red[i];
  scL[tid] = e * __builtin_amdgcn_rcpf(tot);
  __syncthreads();
  const u16* fb = featsP + (size_t)b*PROWS*FEAT;
  float acc = 0.f;
  for (int hw = 0; hw < HWD; ++hw){
    int rowP = hw + 2*(hw >> 6) + 67;
    acc = __builtin_fmaf(b2f(fb[(size_t)rowP*FEAT + tid]), scL[hw], acc);
  }
  gl[tid] = acc;
  __syncthreads();
  int vg = tid >> 7, vv = tid & 127;
  int vc = vv < VOCABP1 ? vv : VOCABP1-1;
  const float* wr = outw + (size_t)vc*512 + vg*128;
  float so = 0.f;
  for (int k = 0; k < 128; k += 4){
    float4 w4 = *(const float4*)&wr[k];
    so += w4.x*gl[vg*128+k] + w4.y*gl[vg*128+k+1] + w4.z*gl[vg*128+k+2] + w4.w*gl[vg*128+k+3];
  }
  part[vg][vv] = so;
  __syncthreads();
  if (tid < VOCABP1)
    out[(size_t)bt*VOCABP1 + tid] = part[0][tid] + part[1][tid] + part[2][tid] + part[3][tid] + outb[tid];
}

extern "C" void kernel_launch(void* const* d_in, const int* in_sizes, int n_in,
                              void* d_out, int out_size, void* d_ws, size_t ws_size,
                              hipStream_t stream){
  (void)in_sizes; (void)n_in; (void)out_size; (void)ws_size;
  const float* features = (const float*)d_in[0];
  const float* encoded  = (const float*)d_in[1];
  const float* embed_w  = (const float*)d_in[2];
  const float* dec_Wih  = (const float*)d_in[3];
  const float* dec_bih  = (const float*)d_in[5];
  const float* dec_bhh  = (const float*)d_in[6];
  const float* att_Wih  = (const float*)d_in[7];
  const float* att_Whh  = (const float*)d_in[8];
  const float* att_bih  = (const float*)d_in[9];
  const float* att_bhh  = (const float*)d_in[10];
  const float* fconv_w  = (const float*)d_in[11];
  const float* fconv_b  = (const float*)d_in[12];
  const float* scw      = (const float*)d_in[13];
  const float* apw      = (const float*)d_in[14];
  const float* outw     = (const float*)d_in[15];
  const float* outb     = (const float*)d_in[16];
  const int* gt         = (const int*)d_in[17];

  char* ws = (char*)d_ws;
  u16*  featsP = (u16*)(ws + 0);            // 10,813,440
  u16*  wB     = (u16*)(ws + 10813440);     //  4,718,592
  float* fpe   = (float*)(ws + 15532032);   // 16,777,216
  u16*  wA1    = (u16*)(ws + 32309248);     //  4,194,304
  u16*  wA2    = (u16*)(ws + 36503552);     //  4,194,304
  u16*  wScw   = (u16*)(ws + 40697856);     //    524,288
  u16*  wEmb   = (u16*)(ws + 41222144);     //    113,664
  float* bsumI = (float*)(ws + 41335808);   //      8,192
  u16*  h0b    = (u16*)(ws + 41344000);     //     16,384
  float* c0    = (float*)(ws + 41360384);   //     32,768
  u16*  h1b    = (u16*)(ws + 41393152);     //    491,520
  float* c1    = (float*)(ws + 41884672);   //    983,040
  u16*  h2b    = (u16*)(ws + 42867712);     //    491,520
  float* spe   = (float*)(ws + 43359232);   //    983,040
  float* sc    = (float*)(ws + 44342272);   //    983,040 -> total 45,325,312 B

  k_prep<<<dim3(2704), 256, 0, stream>>>(features, fconv_w, att_Wih, att_Whh, scw, embed_w,
                                         att_bih, att_bhh, encoded, dec_Wih, dec_bih, dec_bhh,
                                         featsP, wB, wA1, wA2, wScw, wEmb, bsumI, h0b, c0);
  k_conv_gemm1<<<dim3(640), 256, 0, stream>>>(featsP, wB, fconv_b, fpe,
                                              wA1, wEmb, h0b, gt, bsumI, c0, h1b, c1);
  k_gemm_lstm2<<<dim3(16,8), 256, 0, stream>>>(wA2, h1b, h0b, bsumI, c1, h2b);
  k_gemm_spe<<<dim3(4,8), 256, 0, stream>>>(wScw, h2b, spe);
  k_sc<<<dim3(16,16,4), 512, 0, stream>>>(fpe, spe, apw, sc);
  k_tail<<<dim3(480), 512, 0, stream>>>(sc, featsP, outw, outb, (float*)d_out);
}